// Round 1
// baseline (1763.528 us; speedup 1.0000x reference)
//
#include <hip/hip_runtime.h>
#include <hip/hip_bf16.h>

typedef __attribute__((ext_vector_type(4))) float f32x4_t;
typedef __attribute__((ext_vector_type(8))) short bf16x8_t;

__device__ __forceinline__ float bf2f(ushort u) {
  return __uint_as_float(((unsigned)u) << 16);
}
__device__ __forceinline__ ushort f2bf(float f) {
  unsigned u = __float_as_uint(f);
  u += 0x7fffu + ((u >> 16) & 1u);
  return (ushort)(u >> 16);
}

// ---- K1a: x (f32) -> xb (bf16), vectorized 4-wide ----
__global__ void conv_x_kernel(const float* __restrict__ x, ushort* __restrict__ xb, long n4) {
  long i = (long)blockIdx.x * blockDim.x + threadIdx.x;
  long st = (long)gridDim.x * blockDim.x;
  for (; i < n4; i += st) {
    float4 v = ((const float4*)x)[i];
    ushort4 o;
    o.x = f2bf(v.x); o.y = f2bf(v.y); o.z = f2bf(v.z); o.w = f2bf(v.w);
    ((ushort4*)xb)[i] = o;
  }
}

// ---- K1b: wT[r][o][i] = bf16(W[r][i][o]); slot r==R is w_self ----
__global__ void build_wT(const float* __restrict__ rel, const float* __restrict__ wself,
                         ushort* __restrict__ wT, int R) {
  int id = blockIdx.x * blockDim.x + threadIdx.x;
  int total = (R + 1) * 128 * 128;
  if (id >= total) return;
  int r = id >> 14;
  int rem = id & 16383;
  int o = rem >> 7;
  int i = rem & 127;
  float v = (r < R) ? rel[((size_t)r << 14) + (i << 7) + o] : wself[(i << 7) + o];
  wT[id] = f2bf(v);
}

// ---- K1c: in-degree ----
__global__ void deg_kernel(const int* __restrict__ dst, int* __restrict__ deg, long E) {
  long i = (long)blockIdx.x * blockDim.x + threadIdx.x;
  long st = (long)gridDim.x * blockDim.x;
  for (; i < E; i += st) atomicAdd(&deg[dst[i]], 1);
}

// ---- K2: xw[n][r][o] = bf16( (x @ W_r)[n][o] ), r in 0..NR-1 (last = self) ----
// Block = 256 threads = 4 waves; each wave owns 16 rows; A-frags in registers
// across all relations; B-frags 16B loads from hot 295KB wT.
__global__ __launch_bounds__(256) void xw_gemm(const ushort* __restrict__ xb,
                                               const ushort* __restrict__ wT,
                                               ushort* __restrict__ xw,
                                               int N, int NR) {
  const int lane = threadIdx.x & 63;
  const int wave = threadIdx.x >> 6;
  const int rowbase = blockIdx.x * 64 + wave * 16;
  const int l15 = lane & 15;
  const int l4 = lane >> 4;

  int ra = rowbase + l15;
  if (ra > N - 1) ra = N - 1;  // clamp for tail; stores are predicated

  bf16x8_t a[4];
  const ushort* xrow = xb + (size_t)ra * 128 + l4 * 8;
#pragma unroll
  for (int kk = 0; kk < 4; kk++) a[kk] = *(const bf16x8_t*)(xrow + kk * 32);

  for (int r = 0; r < NR; r++) {
    const ushort* wr = wT + ((size_t)r << 14);
#pragma unroll
    for (int nt = 0; nt < 8; nt++) {
      f32x4_t acc = {0.f, 0.f, 0.f, 0.f};
      const ushort* wb = wr + (size_t)(nt * 16 + l15) * 128 + l4 * 8;
#pragma unroll
      for (int kk = 0; kk < 4; kk++) {
        bf16x8_t b = *(const bf16x8_t*)(wb + kk * 32);
        acc = __builtin_amdgcn_mfma_f32_16x16x32_bf16(a[kk], b, acc, 0, 0, 0);
      }
#pragma unroll
      for (int j = 0; j < 4; j++) {
        int row = rowbase + l4 * 4 + j;  // C/D: row=(lane>>4)*4+j, col=lane&15
        if (row < N) xw[((size_t)row * NR + r) * 128 + nt * 16 + l15] = f2bf(acc[j]);
      }
    }
  }
}

// ---- K3: per-edge gather + scatter-add (one wave per edge) ----
__global__ void scatter_kernel(const ushort* __restrict__ xw, const int* __restrict__ src,
                               const int* __restrict__ dst, const int* __restrict__ et,
                               float* __restrict__ agg, long E, int NR) {
  const int lane = threadIdx.x & 63;
  long wid = ((long)blockIdx.x * blockDim.x + threadIdx.x) >> 6;
  long nw = ((long)gridDim.x * blockDim.x) >> 6;
  for (long e = wid; e < E; e += nw) {
    int s = src[e];
    int d = dst[e];
    int t = et[e];
    ushort2 m = *(const ushort2*)(xw + ((size_t)s * NR + t) * 128 + lane * 2);
    float* ap = agg + (size_t)d * 128 + lane * 2;
    atomicAdd(ap, bf2f(m.x));
    atomicAdd(ap + 1, bf2f(m.y));
  }
}

// ---- K4: out = relu(self + b + agg/deg) ----
__global__ void finalize_kernel(const ushort* __restrict__ xw, const float* __restrict__ b,
                                const int* __restrict__ deg, float* __restrict__ out,
                                long total, int NR, int R) {
  long i = (long)blockIdx.x * blockDim.x + threadIdx.x;
  long st = (long)gridDim.x * blockDim.x;
  for (; i < total; i += st) {
    long v = i >> 7;
    int o = (int)(i & 127);
    float self = bf2f(xw[((size_t)v * NR + R) * 128 + o]);
    float dg = (float)max(deg[v], 1);
    float val = self + b[o] + out[i] / dg;
    out[i] = fmaxf(val, 0.f);
  }
}

// ---- Fallback (small workspace): naive per-edge f32 GEMV ----
__global__ void naive_edge(const float* __restrict__ x, const int* __restrict__ src,
                           const int* __restrict__ dst, const int* __restrict__ et,
                           const float* __restrict__ rel, float* __restrict__ agg, long E) {
  const int lane = threadIdx.x & 63;
  long wid = ((long)blockIdx.x * blockDim.x + threadIdx.x) >> 6;
  long nw = ((long)gridDim.x * blockDim.x) >> 6;
  for (long e = wid; e < E; e += nw) {
    int s = src[e];
    int d = dst[e];
    int t = et[e];
    const float* xs = x + (size_t)s * 128;
    const float* w = rel + (size_t)t * 128 * 128;
    float a0 = 0.f, a1 = 0.f;
    for (int i = 0; i < 128; i++) {
      float xv = xs[i];
      a0 += xv * w[i * 128 + lane];
      a1 += xv * w[i * 128 + lane + 64];
    }
    atomicAdd(agg + (size_t)d * 128 + lane, a0);
    atomicAdd(agg + (size_t)d * 128 + lane + 64, a1);
  }
}
__global__ void naive_self(const float* __restrict__ x, const float* __restrict__ ws,
                           const float* __restrict__ b, const int* __restrict__ deg,
                           float* __restrict__ out, int N) {
  int v = blockIdx.x;
  int o = threadIdx.x;
  if (v >= N) return;
  const float* xv = x + (size_t)v * 128;
  float acc = b[o];
  for (int i = 0; i < 128; i++) acc += xv[i] * ws[i * 128 + o];
  float dg = (float)max(deg[v], 1);
  float val = acc + out[(size_t)v * 128 + o] / dg;
  out[(size_t)v * 128 + o] = fmaxf(val, 0.f);
}

extern "C" void kernel_launch(void* const* d_in, const int* in_sizes, int n_in,
                              void* d_out, int out_size, void* d_ws, size_t ws_size,
                              hipStream_t stream) {
  const float* x = (const float*)d_in[0];
  const int* ei = (const int*)d_in[1];
  const int* et = (const int*)d_in[2];
  const float* rel = (const float*)d_in[3];
  const float* wself = (const float*)d_in[4];
  const float* bself = (const float*)d_in[5];
  float* out = (float*)d_out;

  const int N = in_sizes[0] / 128;
  const long E = in_sizes[2];
  const int R = in_sizes[3] / (128 * 128);
  const int NR = R + 1;
  const int* srcp = ei;
  const int* dstp = ei + E;

  // workspace layout
  size_t off = 0;
  int* deg = (int*)((char*)d_ws + off);
  off += ((size_t)N * 4 + 255) & ~(size_t)255;
  size_t xb_off = off;
  off += ((size_t)N * 128 * 2 + 255) & ~(size_t)255;
  size_t wT_off = off;
  off += ((size_t)NR * 128 * 128 * 2 + 255) & ~(size_t)255;
  size_t xw_off = off;
  off += (size_t)N * NR * 128 * 2;
  const bool main_path = (ws_size >= off);

  hipMemsetAsync(d_out, 0, (size_t)out_size * 4, stream);
  hipMemsetAsync(deg, 0, (size_t)N * 4, stream);
  deg_kernel<<<2048, 256, 0, stream>>>(dstp, deg, E);

  if (main_path) {
    ushort* xb = (ushort*)((char*)d_ws + xb_off);
    ushort* wT = (ushort*)((char*)d_ws + wT_off);
    ushort* xw = (ushort*)((char*)d_ws + xw_off);
    conv_x_kernel<<<2048, 256, 0, stream>>>(x, xb, (long)N * 128 / 4);
    build_wT<<<(NR * 16384 + 255) / 256, 256, 0, stream>>>(rel, wself, wT, R);
    xw_gemm<<<(N + 63) / 64, 256, 0, stream>>>(xb, wT, xw, N, NR);
    scatter_kernel<<<2048, 256, 0, stream>>>(xw, srcp, dstp, et, out, E, NR);
    finalize_kernel<<<2048, 256, 0, stream>>>(xw, bself, deg, out, (long)N * 128, NR, R);
  } else {
    naive_edge<<<4096, 256, 0, stream>>>(x, srcp, dstp, et, rel, out, E);
    naive_self<<<N, 128, 0, stream>>>(x, wself, bself, deg, out, N);
  }
}

// Round 2
// 681.659 us; speedup vs baseline: 2.5871x; 2.5871x over previous
//
#include <hip/hip_runtime.h>
#include <hip/hip_bf16.h>

typedef __attribute__((ext_vector_type(4))) float f32x4_t;
typedef __attribute__((ext_vector_type(8))) short bf16x8_t;

__device__ __forceinline__ float bf2f(ushort u) {
  return __uint_as_float(((unsigned)u) << 16);
}
__device__ __forceinline__ ushort f2bf(float f) {
  unsigned u = __float_as_uint(f);
  u += 0x7fffu + ((u >> 16) & 1u);
  return (ushort)(u >> 16);
}

// ---- histogram of dst -> deg ----
__global__ void deg_kernel(const int* __restrict__ dst, int* __restrict__ deg, long E) {
  long i = (long)blockIdx.x * blockDim.x + threadIdx.x;
  long st = (long)gridDim.x * blockDim.x;
  for (; i < E; i += st) atomicAdd(&deg[dst[i]], 1);
}

// ---- exclusive scan over deg (3 kernels) ----
// scan1: each block scans a 1024-chunk; chunk total -> bsum[blockIdx]
__global__ __launch_bounds__(256) void scan1(const int* __restrict__ deg, int* __restrict__ starts,
                                             int* __restrict__ bsum, int N) {
  __shared__ int lds[256];
  const int tid = threadIdx.x;
  const int base = blockIdx.x * 1024 + tid * 4;
  int v0 = 0, v1 = 0, v2 = 0, v3 = 0;
  if (base + 3 < N) {
    int4 q = *(const int4*)(deg + base);
    v0 = q.x; v1 = q.y; v2 = q.z; v3 = q.w;
  } else {
    if (base + 0 < N) v0 = deg[base];
    if (base + 1 < N) v1 = deg[base + 1];
    if (base + 2 < N) v2 = deg[base + 2];
    if (base + 3 < N) v3 = deg[base + 3];
  }
  int s = v0 + v1 + v2 + v3;
  lds[tid] = s;
  __syncthreads();
  for (int off = 1; off < 256; off <<= 1) {
    int t = (tid >= off) ? lds[tid - off] : 0;
    __syncthreads();
    lds[tid] += t;
    __syncthreads();
  }
  int p = lds[tid] - s;  // exclusive prefix of this thread's 4-group
  if (tid == 255) bsum[blockIdx.x] = lds[255];
  if (base + 0 < N) starts[base + 0] = p; p += v0;
  if (base + 1 < N) starts[base + 1] = p; p += v1;
  if (base + 2 < N) starts[base + 2] = p; p += v2;
  if (base + 3 < N) starts[base + 3] = p;
}

// scan2: serial exclusive scan of the ~98 block sums
__global__ void scan2(int* __restrict__ bsum, int nb) {
  if (threadIdx.x == 0 && blockIdx.x == 0) {
    int acc = 0;
    for (int i = 0; i < nb; i++) { int t = bsum[i]; bsum[i] = acc; acc += t; }
  }
}

// scan3: add chunk offsets; also init cursor copy
__global__ void scan3(int* __restrict__ starts, int* __restrict__ cursor,
                      const int* __restrict__ bsum, int N) {
  int i = blockIdx.x * 256 + threadIdx.x;
  if (i < N) {
    int v = starts[i] + bsum[i >> 10];
    starts[i] = v;
    cursor[i] = v;
  }
}

// ---- fill CSR: packed[pos] = (src << 4) | type ----
__global__ void fill_csr(const int* __restrict__ src, const int* __restrict__ dst,
                         const int* __restrict__ et, int* __restrict__ cursor,
                         uint* __restrict__ packed, long E) {
  long i = (long)blockIdx.x * blockDim.x + threadIdx.x;
  long st = (long)gridDim.x * blockDim.x;
  for (; i < E; i += st) {
    int pos = atomicAdd(&cursor[dst[i]], 1);
    packed[pos] = ((uint)src[i] << 4) | (uint)et[i];
  }
}

// ---- wT[r][o][i] = bf16(W[r][i][o]); slot r==R is w_self ----
__global__ void build_wT(const float* __restrict__ rel, const float* __restrict__ wself,
                         ushort* __restrict__ wT, int R) {
  int id = blockIdx.x * blockDim.x + threadIdx.x;
  int total = (R + 1) * 128 * 128;
  if (id >= total) return;
  int r = id >> 14;
  int rem = id & 16383;
  int o = rem >> 7;
  int i = rem & 127;
  float v = (r < R) ? rel[((size_t)r << 14) + (i << 7) + o] : wself[(i << 7) + o];
  wT[id] = f2bf(v);
}

// ---- xw[n][r][o] = bf16( (x @ W_r)[n][o] ), r in 0..NR-1 (last = self) ----
// mfma(A=W-frag, B=x-frag): D-row = out-dim o (4 consecutive per lane -> 8B
// packed store), D-col = node. f32->bf16 A-conversion fused (no xb pass).
__global__ __launch_bounds__(256) void xw_gemm(const float* __restrict__ x,
                                               const ushort* __restrict__ wT,
                                               ushort* __restrict__ xw,
                                               int N, int NR) {
  const int lane = threadIdx.x & 63;
  const int wave = threadIdx.x >> 6;
  const int nodebase = blockIdx.x * 64 + wave * 16;
  const int l15 = lane & 15;
  const int l4 = lane >> 4;

  int ra = nodebase + l15;
  if (ra > N - 1) ra = N - 1;  // clamp tail reads; stores predicated
  const float* xrow = x + (size_t)ra * 128 + l4 * 8;
  bf16x8_t xf[4];
#pragma unroll
  for (int kk = 0; kk < 4; kk++) {
    float4 v0 = *(const float4*)(xrow + kk * 32);
    float4 v1 = *(const float4*)(xrow + kk * 32 + 4);
    bf16x8_t t;
    t[0] = (short)f2bf(v0.x); t[1] = (short)f2bf(v0.y);
    t[2] = (short)f2bf(v0.z); t[3] = (short)f2bf(v0.w);
    t[4] = (short)f2bf(v1.x); t[5] = (short)f2bf(v1.y);
    t[6] = (short)f2bf(v1.z); t[7] = (short)f2bf(v1.w);
    xf[kk] = t;
  }
  const int node = nodebase + l15;

  for (int r = 0; r < NR; r++) {
    const ushort* wr = wT + ((size_t)r << 14);
#pragma unroll
    for (int nt = 0; nt < 8; nt++) {
      f32x4_t acc = {0.f, 0.f, 0.f, 0.f};
      const ushort* wb = wr + (size_t)(nt * 16 + l15) * 128 + l4 * 8;
#pragma unroll
      for (int kk = 0; kk < 4; kk++) {
        bf16x8_t w = *(const bf16x8_t*)(wb + kk * 32);
        acc = __builtin_amdgcn_mfma_f32_16x16x32_bf16(w, xf[kk], acc, 0, 0, 0);
      }
      if (node < N) {
        ushort4 pk;
        pk.x = f2bf(acc[0]); pk.y = f2bf(acc[1]);
        pk.z = f2bf(acc[2]); pk.w = f2bf(acc[3]);
        *(ushort4*)(xw + ((size_t)node * NR + r) * 128 + nt * 16 + l4 * 4) = pk;
      }
    }
  }
}

// ---- gather + fused finalize: one wave per dst node ----
__global__ __launch_bounds__(256) void gather_out(const ushort* __restrict__ xw,
                                                  const uint* __restrict__ packed,
                                                  const int* __restrict__ starts,
                                                  const int* __restrict__ deg,
                                                  const float* __restrict__ b,
                                                  float* __restrict__ out,
                                                  int N, int NR, int R) {
  const int lane = threadIdx.x & 63;
  const int d = blockIdx.x * 4 + (threadIdx.x >> 6);
  if (d >= N) return;
  const int s0 = starts[d];
  const int dg = deg[d];
  const int e1 = s0 + dg;
  float a0 = 0.f, a1 = 0.f;
  int e = s0;
  for (; e + 1 < e1; e += 2) {
    uint r0 = packed[e], r1 = packed[e + 1];
    ushort2 m0 = *(const ushort2*)(xw + ((size_t)(r0 >> 4) * NR + (r0 & 15u)) * 128 + lane * 2);
    ushort2 m1 = *(const ushort2*)(xw + ((size_t)(r1 >> 4) * NR + (r1 & 15u)) * 128 + lane * 2);
    a0 += bf2f(m0.x) + bf2f(m1.x);
    a1 += bf2f(m0.y) + bf2f(m1.y);
  }
  if (e < e1) {
    uint r0 = packed[e];
    ushort2 m0 = *(const ushort2*)(xw + ((size_t)(r0 >> 4) * NR + (r0 & 15u)) * 128 + lane * 2);
    a0 += bf2f(m0.x);
    a1 += bf2f(m0.y);
  }
  float inv = 1.0f / (float)((dg > 1) ? dg : 1);
  ushort2 sf = *(const ushort2*)(xw + ((size_t)d * NR + R) * 128 + lane * 2);
  float2 bb = ((const float2*)b)[lane];
  float* op = out + (size_t)d * 128 + lane * 2;
  op[0] = fmaxf(bf2f(sf.x) + bb.x + a0 * inv, 0.f);
  op[1] = fmaxf(bf2f(sf.y) + bb.y + a1 * inv, 0.f);
}

// ---- Fallback (small workspace): naive per-edge f32 GEMV ----
__global__ void naive_edge(const float* __restrict__ x, const int* __restrict__ src,
                           const int* __restrict__ dst, const int* __restrict__ et,
                           const float* __restrict__ rel, float* __restrict__ agg, long E) {
  const int lane = threadIdx.x & 63;
  long wid = ((long)blockIdx.x * blockDim.x + threadIdx.x) >> 6;
  long nw = ((long)gridDim.x * blockDim.x) >> 6;
  for (long e = wid; e < E; e += nw) {
    int s = src[e];
    int d = dst[e];
    int t = et[e];
    const float* xs = x + (size_t)s * 128;
    const float* w = rel + (size_t)t * 128 * 128;
    float a0 = 0.f, a1 = 0.f;
    for (int i = 0; i < 128; i++) {
      float xv = xs[i];
      a0 += xv * w[i * 128 + lane];
      a1 += xv * w[i * 128 + lane + 64];
    }
    atomicAdd(agg + (size_t)d * 128 + lane, a0);
    atomicAdd(agg + (size_t)d * 128 + lane + 64, a1);
  }
}
__global__ void naive_self(const float* __restrict__ x, const float* __restrict__ ws,
                           const float* __restrict__ b, const int* __restrict__ deg,
                           float* __restrict__ out, int N) {
  int v = blockIdx.x;
  int o = threadIdx.x;
  if (v >= N) return;
  const float* xv = x + (size_t)v * 128;
  float acc = b[o];
  for (int i = 0; i < 128; i++) acc += xv[i] * ws[i * 128 + o];
  float dg = (float)max(deg[v], 1);
  float val = acc + out[(size_t)v * 128 + o] / dg;
  out[(size_t)v * 128 + o] = fmaxf(val, 0.f);
}

extern "C" void kernel_launch(void* const* d_in, const int* in_sizes, int n_in,
                              void* d_out, int out_size, void* d_ws, size_t ws_size,
                              hipStream_t stream) {
  const float* x = (const float*)d_in[0];
  const int* ei = (const int*)d_in[1];
  const int* et = (const int*)d_in[2];
  const float* rel = (const float*)d_in[3];
  const float* wself = (const float*)d_in[4];
  const float* bself = (const float*)d_in[5];
  float* out = (float*)d_out;

  const int N = in_sizes[0] / 128;
  const long E = in_sizes[2];
  const int R = in_sizes[3] / (128 * 128);
  const int NR = R + 1;
  const int* srcp = ei;
  const int* dstp = ei + E;

  // workspace layout (all 256B-aligned)
  size_t off = 0;
  auto alloc = [&](size_t bytes) {
    size_t o = off;
    off += (bytes + 255) & ~(size_t)255;
    return o;
  };
  size_t deg_off = alloc((size_t)N * 4);
  size_t starts_off = alloc((size_t)N * 4);
  size_t cursor_off = alloc((size_t)N * 4);
  size_t bsum_off = alloc(4096);
  size_t wT_off = alloc((size_t)NR * 128 * 128 * 2);
  size_t packed_off = alloc((size_t)E * 4);
  size_t xw_off = alloc((size_t)N * (size_t)NR * 128 * 2);
  const bool main_path = (ws_size >= off);

  int* deg = (int*)((char*)d_ws + deg_off);
  hipMemsetAsync(deg, 0, (size_t)N * 4, stream);
  deg_kernel<<<2048, 256, 0, stream>>>(dstp, deg, E);

  if (main_path) {
    int* starts = (int*)((char*)d_ws + starts_off);
    int* cursor = (int*)((char*)d_ws + cursor_off);
    int* bsum = (int*)((char*)d_ws + bsum_off);
    ushort* wT = (ushort*)((char*)d_ws + wT_off);
    uint* packed = (uint*)((char*)d_ws + packed_off);
    ushort* xw = (ushort*)((char*)d_ws + xw_off);

    const int nb = (N + 1023) / 1024;
    scan1<<<nb, 256, 0, stream>>>(deg, starts, bsum, N);
    scan2<<<1, 64, 0, stream>>>(bsum, nb);
    scan3<<<(N + 255) / 256, 256, 0, stream>>>(starts, cursor, bsum, N);
    fill_csr<<<2048, 256, 0, stream>>>(srcp, dstp, et, cursor, packed, E);
    build_wT<<<(NR * 16384 + 255) / 256, 256, 0, stream>>>(rel, wself, wT, R);
    xw_gemm<<<(N + 63) / 64, 256, 0, stream>>>(x, wT, xw, N, NR);
    gather_out<<<(N + 3) / 4, 256, 0, stream>>>(xw, packed, starts, deg, bself, out, N, NR, R);
  } else {
    hipMemsetAsync(out, 0, (size_t)out_size * 4, stream);
    naive_edge<<<4096, 256, 0, stream>>>(x, srcp, dstp, et, rel, out, E);
    naive_self<<<N, 128, 0, stream>>>(x, wself, bself, deg, out, N);
  }
}

// Round 3
// 531.337 us; speedup vs baseline: 3.3190x; 1.2829x over previous
//
#include <hip/hip_runtime.h>
#include <hip/hip_bf16.h>

typedef __attribute__((ext_vector_type(4))) float f32x4_t;
typedef __attribute__((ext_vector_type(8))) short bf16x8_t;

__device__ __forceinline__ float bf2f(ushort u) {
  return __uint_as_float(((unsigned)u) << 16);
}
__device__ __forceinline__ ushort f2bf(float f) {
  unsigned u = __float_as_uint(f);
  u += 0x7fffu + ((u >> 16) & 1u);
  return (ushort)(u >> 16);
}

// ---- histogram of dst -> deg ----
__global__ void deg_kernel(const int* __restrict__ dst, int* __restrict__ deg, long E) {
  long i = (long)blockIdx.x * blockDim.x + threadIdx.x;
  long st = (long)gridDim.x * blockDim.x;
  for (; i < E; i += st) atomicAdd(&deg[dst[i]], 1);
}

// ---- exclusive scan over deg (3 kernels) ----
__global__ __launch_bounds__(256) void scan1(const int* __restrict__ deg, int* __restrict__ starts,
                                             int* __restrict__ bsum, int N) {
  __shared__ int lds[256];
  const int tid = threadIdx.x;
  const int base = blockIdx.x * 1024 + tid * 4;
  int v0 = 0, v1 = 0, v2 = 0, v3 = 0;
  if (base + 3 < N) {
    int4 q = *(const int4*)(deg + base);
    v0 = q.x; v1 = q.y; v2 = q.z; v3 = q.w;
  } else {
    if (base + 0 < N) v0 = deg[base];
    if (base + 1 < N) v1 = deg[base + 1];
    if (base + 2 < N) v2 = deg[base + 2];
    if (base + 3 < N) v3 = deg[base + 3];
  }
  int s = v0 + v1 + v2 + v3;
  lds[tid] = s;
  __syncthreads();
  for (int off = 1; off < 256; off <<= 1) {
    int t = (tid >= off) ? lds[tid - off] : 0;
    __syncthreads();
    lds[tid] += t;
    __syncthreads();
  }
  int p = lds[tid] - s;
  if (tid == 255) bsum[blockIdx.x] = lds[255];
  if (base + 0 < N) starts[base + 0] = p; p += v0;
  if (base + 1 < N) starts[base + 1] = p; p += v1;
  if (base + 2 < N) starts[base + 2] = p; p += v2;
  if (base + 3 < N) starts[base + 3] = p;
}

__global__ void scan2(int* __restrict__ bsum, int nb) {
  if (threadIdx.x == 0 && blockIdx.x == 0) {
    int acc = 0;
    for (int i = 0; i < nb; i++) { int t = bsum[i]; bsum[i] = acc; acc += t; }
  }
}

__global__ void scan3(int* __restrict__ starts, int* __restrict__ cursor,
                      const int* __restrict__ bsum, int N) {
  int i = blockIdx.x * 256 + threadIdx.x;
  if (i < N) {
    int v = starts[i] + bsum[i >> 10];
    starts[i] = v;
    cursor[i] = v;
  }
}

// ---- fill CSR: packed[pos] = (src << 4) | type ----
__global__ void fill_csr(const int* __restrict__ src, const int* __restrict__ dst,
                         const int* __restrict__ et, int* __restrict__ cursor,
                         uint* __restrict__ packed, long E) {
  long i = (long)blockIdx.x * blockDim.x + threadIdx.x;
  long st = (long)gridDim.x * blockDim.x;
  for (; i < E; i += st) {
    int pos = atomicAdd(&cursor[dst[i]], 1);
    packed[pos] = ((uint)src[i] << 4) | (uint)et[i];
  }
}

// ---- wT[r][o][i] = bf16(W[r][i][o]); slot r==R is w_self ----
__global__ void build_wT(const float* __restrict__ rel, const float* __restrict__ wself,
                         ushort* __restrict__ wT, int R) {
  int id = blockIdx.x * blockDim.x + threadIdx.x;
  int total = (R + 1) * 128 * 128;
  if (id >= total) return;
  int r = id >> 14;
  int rem = id & 16383;
  int o = rem >> 7;
  int i = rem & 127;
  float v = (r < R) ? rel[((size_t)r << 14) + (i << 7) + o] : wself[(i << 7) + o];
  wT[id] = f2bf(v);
}

// ---- xw[n][r][o] = bf16( (x @ W_r)[n][o] ) ----
// 8 waves x 32 nodes = 256 nodes/block. W_r staged per relation into
// double-buffered, XOR-swizzled LDS (conflict-free ds_read_b128);
// T14 split: next-relation global loads issued before the MFMA cluster,
// LDS writes after. x-frags live in registers across all relations.
__global__ __launch_bounds__(512) void xw_gemm(const float* __restrict__ x,
                                               const ushort* __restrict__ wT,
                                               ushort* __restrict__ xw,
                                               int N, int NR) {
  __shared__ ushort smem[2][16384];  // 2 x 32KB

  const int tid = threadIdx.x;
  const int lane = tid & 63;
  const int wave = tid >> 6;
  const int l15 = lane & 15;
  const int l4 = lane >> 4;
  const int nodebase = blockIdx.x * 256 + wave * 32;

  // ---- load x-frags for 2 node groups (f32 -> bf16 fused) ----
  bf16x8_t xf[2][4];
  int nd[2];
#pragma unroll
  for (int g = 0; g < 2; g++) {
    int node = nodebase + g * 16 + l15;
    nd[g] = node;
    int ra = (node < N) ? node : (N - 1);
    const float* xrow = x + (size_t)ra * 128 + l4 * 8;
#pragma unroll
    for (int kk = 0; kk < 4; kk++) {
      float4 v0 = *(const float4*)(xrow + kk * 32);
      float4 v1 = *(const float4*)(xrow + kk * 32 + 4);
      bf16x8_t t;
      t[0] = (short)f2bf(v0.x); t[1] = (short)f2bf(v0.y);
      t[2] = (short)f2bf(v0.z); t[3] = (short)f2bf(v0.w);
      t[4] = (short)f2bf(v1.x); t[5] = (short)f2bf(v1.y);
      t[6] = (short)f2bf(v1.z); t[7] = (short)f2bf(v1.w);
      xf[g][kk] = t;
    }
  }

  // ---- prologue: stage W_0 into buf 0 ----
  {
    bf16x8_t sreg[4];
#pragma unroll
    for (int j = 0; j < 4; j++) {
      int c = tid + j * 512;
      sreg[j] = *(const bf16x8_t*)(wT + c * 8);
    }
#pragma unroll
    for (int j = 0; j < 4; j++) {
      int c = tid + j * 512;
      int o = c >> 4;
      int colb = (c & 15) * 16;
      int byte = o * 256 + (colb ^ ((o & 7) << 4));
      *(bf16x8_t*)((char*)smem[0] + byte) = sreg[j];
    }
  }
  __syncthreads();

  for (int r = 0; r < NR; r++) {
    // issue next relation's global loads (latency hides under MFMA)
    bf16x8_t sreg[4];
    const bool pf = (r + 1 < NR);
    if (pf) {
      const ushort* wsrc = wT + ((size_t)(r + 1) << 14);
#pragma unroll
      for (int j = 0; j < 4; j++) {
        int c = tid + j * 512;
        sreg[j] = *(const bf16x8_t*)(wsrc + c * 8);
      }
    }

    // compute from buf[r&1]
    const char* wbuf = (const char*)smem[r & 1];
#pragma unroll
    for (int nt = 0; nt < 8; nt++) {
      bf16x8_t wf[4];
      const int row = nt * 16 + l15;
      const int swz = (row & 7) << 4;
#pragma unroll
      for (int kk = 0; kk < 4; kk++) {
        int colb = l4 * 16 + kk * 64;
        wf[kk] = *(const bf16x8_t*)(wbuf + row * 256 + (colb ^ swz));
      }
#pragma unroll
      for (int g = 0; g < 2; g++) {
        f32x4_t acc = {0.f, 0.f, 0.f, 0.f};
#pragma unroll
        for (int kk = 0; kk < 4; kk++)
          acc = __builtin_amdgcn_mfma_f32_16x16x32_bf16(wf[kk], xf[g][kk], acc, 0, 0, 0);
        if (nd[g] < N) {
          ushort4 pk;
          pk.x = f2bf(acc[0]); pk.y = f2bf(acc[1]);
          pk.z = f2bf(acc[2]); pk.w = f2bf(acc[3]);
          *(ushort4*)(xw + ((size_t)nd[g] * NR + r) * 128 + nt * 16 + l4 * 4) = pk;
        }
      }
    }

    // write prefetched W into the other buffer, then barrier
    if (pf) {
#pragma unroll
      for (int j = 0; j < 4; j++) {
        int c = tid + j * 512;
        int o = c >> 4;
        int colb = (c & 15) * 16;
        int byte = o * 256 + (colb ^ ((o & 7) << 4));
        *(bf16x8_t*)((char*)smem[(r + 1) & 1] + byte) = sreg[j];
      }
    }
    __syncthreads();
  }
}

// ---- gather + fused finalize: one wave per dst node ----
__global__ __launch_bounds__(256) void gather_out(const ushort* __restrict__ xw,
                                                  const uint* __restrict__ packed,
                                                  const int* __restrict__ starts,
                                                  const int* __restrict__ deg,
                                                  const float* __restrict__ b,
                                                  float* __restrict__ out,
                                                  int N, int NR, int R) {
  const int lane = threadIdx.x & 63;
  const int d = blockIdx.x * 4 + (threadIdx.x >> 6);
  if (d >= N) return;
  const int s0 = starts[d];
  const int dg = deg[d];
  const int e1 = s0 + dg;
  float a0 = 0.f, a1 = 0.f;
  int e = s0;
  for (; e + 1 < e1; e += 2) {
    uint r0 = packed[e], r1 = packed[e + 1];
    ushort2 m0 = *(const ushort2*)(xw + ((size_t)(r0 >> 4) * NR + (r0 & 15u)) * 128 + lane * 2);
    ushort2 m1 = *(const ushort2*)(xw + ((size_t)(r1 >> 4) * NR + (r1 & 15u)) * 128 + lane * 2);
    a0 += bf2f(m0.x) + bf2f(m1.x);
    a1 += bf2f(m0.y) + bf2f(m1.y);
  }
  if (e < e1) {
    uint r0 = packed[e];
    ushort2 m0 = *(const ushort2*)(xw + ((size_t)(r0 >> 4) * NR + (r0 & 15u)) * 128 + lane * 2);
    a0 += bf2f(m0.x);
    a1 += bf2f(m0.y);
  }
  float inv = 1.0f / (float)((dg > 1) ? dg : 1);
  ushort2 sf = *(const ushort2*)(xw + ((size_t)d * NR + R) * 128 + lane * 2);
  float2 bb = ((const float2*)b)[lane];
  float* op = out + (size_t)d * 128 + lane * 2;
  op[0] = fmaxf(bf2f(sf.x) + bb.x + a0 * inv, 0.f);
  op[1] = fmaxf(bf2f(sf.y) + bb.y + a1 * inv, 0.f);
}

// ---- Fallback (small workspace): naive per-edge f32 GEMV ----
__global__ void naive_edge(const float* __restrict__ x, const int* __restrict__ src,
                           const int* __restrict__ dst, const int* __restrict__ et,
                           const float* __restrict__ rel, float* __restrict__ agg, long E) {
  const int lane = threadIdx.x & 63;
  long wid = ((long)blockIdx.x * blockDim.x + threadIdx.x) >> 6;
  long nw = ((long)gridDim.x * blockDim.x) >> 6;
  for (long e = wid; e < E; e += nw) {
    int s = src[e];
    int d = dst[e];
    int t = et[e];
    const float* xs = x + (size_t)s * 128;
    const float* w = rel + (size_t)t * 128 * 128;
    float a0 = 0.f, a1 = 0.f;
    for (int i = 0; i < 128; i++) {
      float xv = xs[i];
      a0 += xv * w[i * 128 + lane];
      a1 += xv * w[i * 128 + lane + 64];
    }
    atomicAdd(agg + (size_t)d * 128 + lane, a0);
    atomicAdd(agg + (size_t)d * 128 + lane + 64, a1);
  }
}
__global__ void naive_self(const float* __restrict__ x, const float* __restrict__ ws,
                           const float* __restrict__ b, const int* __restrict__ deg,
                           float* __restrict__ out, int N) {
  int v = blockIdx.x;
  int o = threadIdx.x;
  if (v >= N) return;
  const float* xv = x + (size_t)v * 128;
  float acc = b[o];
  for (int i = 0; i < 128; i++) acc += xv[i] * ws[i * 128 + o];
  float dg = (float)max(deg[v], 1);
  float val = acc + out[(size_t)v * 128 + o] / dg;
  out[(size_t)v * 128 + o] = fmaxf(val, 0.f);
}

extern "C" void kernel_launch(void* const* d_in, const int* in_sizes, int n_in,
                              void* d_out, int out_size, void* d_ws, size_t ws_size,
                              hipStream_t stream) {
  const float* x = (const float*)d_in[0];
  const int* ei = (const int*)d_in[1];
  const int* et = (const int*)d_in[2];
  const float* rel = (const float*)d_in[3];
  const float* wself = (const float*)d_in[4];
  const float* bself = (const float*)d_in[5];
  float* out = (float*)d_out;

  const int N = in_sizes[0] / 128;
  const long E = in_sizes[2];
  const int R = in_sizes[3] / (128 * 128);
  const int NR = R + 1;
  const int* srcp = ei;
  const int* dstp = ei + E;

  // workspace layout (all 256B-aligned)
  size_t off = 0;
  auto alloc = [&](size_t bytes) {
    size_t o = off;
    off += (bytes + 255) & ~(size_t)255;
    return o;
  };
  size_t deg_off = alloc((size_t)N * 4);
  size_t starts_off = alloc((size_t)N * 4);
  size_t cursor_off = alloc((size_t)N * 4);
  size_t bsum_off = alloc(4096);
  size_t wT_off = alloc((size_t)NR * 128 * 128 * 2);
  size_t packed_off = alloc((size_t)E * 4);
  size_t xw_off = alloc((size_t)N * (size_t)NR * 128 * 2);
  const bool main_path = (ws_size >= off);

  int* deg = (int*)((char*)d_ws + deg_off);
  hipMemsetAsync(deg, 0, (size_t)N * 4, stream);
  deg_kernel<<<2048, 256, 0, stream>>>(dstp, deg, E);

  if (main_path) {
    int* starts = (int*)((char*)d_ws + starts_off);
    int* cursor = (int*)((char*)d_ws + cursor_off);
    int* bsum = (int*)((char*)d_ws + bsum_off);
    ushort* wT = (ushort*)((char*)d_ws + wT_off);
    uint* packed = (uint*)((char*)d_ws + packed_off);
    ushort* xw = (ushort*)((char*)d_ws + xw_off);

    const int nb = (N + 1023) / 1024;
    scan1<<<nb, 256, 0, stream>>>(deg, starts, bsum, N);
    scan2<<<1, 64, 0, stream>>>(bsum, nb);
    scan3<<<(N + 255) / 256, 256, 0, stream>>>(starts, cursor, bsum, N);
    fill_csr<<<2048, 256, 0, stream>>>(srcp, dstp, et, cursor, packed, E);
    build_wT<<<(NR * 16384 + 255) / 256, 256, 0, stream>>>(rel, wself, wT, R);
    xw_gemm<<<(N + 255) / 256, 512, 0, stream>>>(x, wT, xw, N, NR);
    gather_out<<<(N + 3) / 4, 256, 0, stream>>>(xw, packed, starts, deg, bself, out, N, NR, R);
  } else {
    hipMemsetAsync(out, 0, (size_t)out_size * 4, stream);
    naive_edge<<<4096, 256, 0, stream>>>(x, srcp, dstp, et, rel, out, E);
    naive_self<<<N, 128, 0, stream>>>(x, wself, bself, deg, out, N);
  }
}